// Round 7
// baseline (483.207 us; speedup 1.0000x reference)
//
#include <hip/hip_runtime.h>

#define NDIM 128
#define NBASES 8
#define KDIM 1152            // 8*128 (bases) + 128 (root slot)
#define GTILE 16
#define APITCH 1160          // shorts; row stride 2320 B (16B-divisible)

typedef __attribute__((ext_vector_type(8))) __bf16 bfrag;
typedef __attribute__((ext_vector_type(4))) float f32x4;
typedef __attribute__((ext_vector_type(2))) float f32x2;

__device__ __forceinline__ float bf2f(unsigned short b) {
    return __uint_as_float(((unsigned)b) << 16);
}
__device__ __forceinline__ unsigned short f2bf(float f) {
    unsigned u = __float_as_uint(f);
    unsigned r = u + 0x7FFFu + ((u >> 16) & 1u);   // RNE
    return (unsigned short)(r >> 16);
}
__device__ __forceinline__ unsigned pack2bf(float lo, float hi) {
    return (unsigned)f2bf(lo) | ((unsigned)f2bf(hi) << 16);
}
__device__ __forceinline__ float loadF(const void* p, int idx, int isf32) {
    return isf32 ? ((const float*)p)[idx] : bf2f(((const unsigned short*)p)[idx]);
}

// ---------- dtype sniffing: same single-thread semantics, ILP loads ----------
__global__ void detect_k(const unsigned short* __restrict__ xs,
                         const int* __restrict__ ei, int* __restrict__ meta) {
    if (threadIdx.x != 0 || blockIdx.x != 0) return;
    const uint4* xv = (const uint4*)xs;
    unsigned f32m = 0;
    uint4 bx[16];
    #pragma unroll
    for (int i = 0; i < 16; ++i) bx[i] = xv[i];     // shorts 0..127, independent
    #pragma unroll
    for (int i = 0; i < 16; ++i) {
        unsigned a = bx[i].x, b = bx[i].y, c = bx[i].z, d = bx[i].w;
        f32m |= (((a & 0xFFFFu) >> 7) & 0xFFu) > 124u;
        f32m |= (((b & 0xFFFFu) >> 7) & 0xFFu) > 124u;
        f32m |= (((c & 0xFFFFu) >> 7) & 0xFFu) > 124u;
        f32m |= (((d & 0xFFFFu) >> 7) & 0xFFu) > 124u;
    }
    const uint4* ev = (const uint4*)ei;
    unsigned nzm = 0;
    for (int r = 0; r < 4; ++r) {
        uint4 be[16];
        #pragma unroll
        for (int i = 0; i < 16; ++i) be[i] = ev[r * 16 + i];   // ints 0..255
        #pragma unroll
        for (int i = 0; i < 16; ++i) nzm |= be[i].y | be[i].w; // odd ints
    }
    meta[0] = f32m ? 1 : 0;
    meta[1] = nzm ? 0 : 1;
}

// merged: BT build + special-embedding copy
__global__ void misc_k(const void* __restrict__ basis, const void* __restrict__ root,
                       const void* __restrict__ se, const int* __restrict__ meta,
                       unsigned short* __restrict__ BT, void* __restrict__ out,
                       int scount, int sbase) {
    int t = blockIdx.x * 256 + threadIdx.x;
    int isf32 = meta[0];
    if (t < NDIM * KDIM) {
        int j = t / KDIM, k = t % KDIM;
        float v = (k < NBASES * NDIM) ? loadF(basis, k * NDIM + j, isf32)
                                      : loadF(root, (k - NBASES * NDIM) * NDIM + j, isf32);
        BT[t] = f2bf(v);
    } else {
        int u = t - NDIM * KDIM;
        if (u < scount) {
            float v = loadF(se, u, isf32);
            if (isf32) ((float*)out)[sbase + u] = v;
            else       ((unsigned short*)out)[sbase + u] = f2bf(v);
        }
    }
}

__global__ void hist_k(const int* __restrict__ ei, int E, int N,
                       const int* __restrict__ meta, int* __restrict__ hist) {
    int e = blockIdx.x * 256 + threadIdx.x;
    if (e >= E) return;
    int dst = meta[1] ? ei[2 * (E + e)] : ei[E + e];
    dst = min(max(dst, 0), N - 1);
    atomicAdd(&hist[dst], 1);
}

// single-block exclusive scan (round-2-proven)
__global__ void scan_k(const int* __restrict__ hist, int N, int* __restrict__ offsets) {
    __shared__ int s[1024];
    int tid = threadIdx.x;
    int span = (N + 1023) / 1024;
    int base = tid * span;
    int tot = 0;
    for (int i = 0; i < span; ++i) {
        int idx = base + i;
        if (idx < N) tot += hist[idx];
    }
    s[tid] = tot;
    __syncthreads();
    for (int off = 1; off < 1024; off <<= 1) {
        int v = 0;
        if (tid >= off) v = s[tid - off];
        __syncthreads();
        if (tid >= off) s[tid] += v;
        __syncthreads();
    }
    int run = s[tid] - tot;
    for (int i = 0; i < span; ++i) {
        int idx = base + i;
        if (idx < N) { offsets[idx] = run; run += hist[idx]; }
    }
    if (tid == 1023) offsets[N] = s[1023];
}

__global__ void scatter_k(const int* __restrict__ ei, const int* __restrict__ et,
                          int E, int N, const int* __restrict__ meta,
                          const int* __restrict__ offsets, int* __restrict__ cursor,
                          int* __restrict__ sorted) {
    int e = blockIdx.x * 256 + threadIdx.x;
    if (e >= E) return;
    int i64 = meta[1];
    int src = i64 ? ei[2 * e] : ei[e];
    int dst = i64 ? ei[2 * (E + e)] : ei[E + e];
    int rel = i64 ? et[2 * e] : et[e];
    src = min(max(src, 0), N - 1);
    dst = min(max(dst, 0), N - 1);
    rel = rel & 63;
    int pos = offsets[dst] + atomicAdd(&cursor[dst], 1);
    sorted[pos] = src | (rel << 16);
}

// ---------- main fused kernel: 1 node/wave, 16 waves/block ----------
__global__ __launch_bounds__(1024) void rgcn_main_k(
    const void* __restrict__ x, const void* __restrict__ comp,
    const void* __restrict__ bias, const unsigned short* __restrict__ BT,
    const int* __restrict__ meta, const int* __restrict__ offsets,
    const int* __restrict__ sorted, void* __restrict__ out, int N)
{
    __shared__ alignas(16) unsigned short A_lds[GTILE * APITCH];   // 37120 B
    __shared__ float2 comp_lds[48 * 4];                            // [rel][bs]
    const int tid  = threadIdx.x;
    const int lane = tid & 63;
    const int wave = tid >> 6;
    const int isf32 = meta[0];

    for (int t = tid; t < 48 * NBASES; t += 1024)
        ((float*)comp_lds)[t] = loadF(comp, t, isf32);
    __syncthreads();

    const int nodeBase = blockIdx.x * GTILE;
    const int dg = lane & 15;    // dim group: dims dg*8..+8
    const int bs = lane >> 4;    // basis slot: bases bs*2, bs*2+1

    {   // ---- Phase A ----
        const int n = nodeBase + wave;
        f32x2 acc[8];            // acc[d] = {basis bs*2, basis bs*2+1} for dim dg*8+d
        #pragma unroll
        for (int i = 0; i < 8; ++i) acc[i] = (f32x2){0.f, 0.f};

        if (n < N) {
            const int start = offsets[n], end = offsets[n + 1];

            // pass 1: per-relation counts (lane r counts rel==r), VALU-only
            int myCnt = 0;
            for (int c = start; c < end; c += 64) {
                int sv = (c + lane < end) ? sorted[c + lane] : -1;
                int mm = min(64, end - c);
                for (int j = 0; j < mm; ++j) {
                    int rv = __shfl(sv, j) >> 16;
                    myCnt += (rv == lane) ? 1 : 0;
                }
            }
            float myCntF = (float)myCnt;

            auto consume = [&](unsigned qq, uint4 xa) {
                int rel = (int)(qq >> 16);
                float cf = __shfl(myCntF, rel);
                float norm = __builtin_amdgcn_rcpf(fmaxf(cf, 1.0f));
                float2 cwf = comp_lds[rel * 4 + bs];
                f32x2 w; w.x = cwf.x * norm; w.y = cwf.y * norm;
                #pragma unroll
                for (int i = 0; i < 4; ++i) {
                    float lo = __uint_as_float(xa[i] << 16);
                    float hi = __uint_as_float(xa[i] & 0xFFFF0000u);
                    f32x2 l2 = {lo, lo}, h2 = {hi, hi};
                    acc[2 * i]     += w * l2;
                    acc[2 * i + 1] += w * h2;
                }
            };

            if (!isf32) {
                const unsigned short* xh = (const unsigned short*)x;
                for (int c = start; c < end; c += 64) {
                    int sv = (c + lane < end) ? sorted[c + lane] : -1;
                    int mm = min(64, end - c);
                    int j = 0;
                    if (mm >= 4) {
                        unsigned qa0 = (unsigned)__shfl(sv, 0);
                        unsigned qa1 = (unsigned)__shfl(sv, 1);
                        unsigned qa2 = (unsigned)__shfl(sv, 2);
                        unsigned qa3 = (unsigned)__shfl(sv, 3);
                        uint4 xa0 = *(const uint4*)(xh + (size_t)(qa0 & 0xFFFFu) * NDIM + dg * 8);
                        uint4 xa1 = *(const uint4*)(xh + (size_t)(qa1 & 0xFFFFu) * NDIM + dg * 8);
                        uint4 xa2 = *(const uint4*)(xh + (size_t)(qa2 & 0xFFFFu) * NDIM + dg * 8);
                        uint4 xa3 = *(const uint4*)(xh + (size_t)(qa3 & 0xFFFFu) * NDIM + dg * 8);
                        for (j = 4; j + 4 <= mm; j += 4) {
                            unsigned qb0 = (unsigned)__shfl(sv, j);
                            unsigned qb1 = (unsigned)__shfl(sv, j + 1);
                            unsigned qb2 = (unsigned)__shfl(sv, j + 2);
                            unsigned qb3 = (unsigned)__shfl(sv, j + 3);
                            uint4 xb0 = *(const uint4*)(xh + (size_t)(qb0 & 0xFFFFu) * NDIM + dg * 8);
                            uint4 xb1 = *(const uint4*)(xh + (size_t)(qb1 & 0xFFFFu) * NDIM + dg * 8);
                            uint4 xb2 = *(const uint4*)(xh + (size_t)(qb2 & 0xFFFFu) * NDIM + dg * 8);
                            uint4 xb3 = *(const uint4*)(xh + (size_t)(qb3 & 0xFFFFu) * NDIM + dg * 8);
                            consume(qa0, xa0); consume(qa1, xa1);
                            consume(qa2, xa2); consume(qa3, xa3);
                            qa0 = qb0; qa1 = qb1; qa2 = qb2; qa3 = qb3;
                            xa0 = xb0; xa1 = xb1; xa2 = xb2; xa3 = xb3;
                        }
                        consume(qa0, xa0); consume(qa1, xa1);
                        consume(qa2, xa2); consume(qa3, xa3);
                    }
                    for (; j < mm; ++j) {
                        unsigned qq = (unsigned)__shfl(sv, j);
                        uint4 xa = *(const uint4*)(xh + (size_t)(qq & 0xFFFFu) * NDIM + dg * 8);
                        consume(qq, xa);
                    }
                }
            } else {
                const float* xf = (const float*)x;
                for (int c = start; c < end; c += 64) {
                    int sv = (c + lane < end) ? sorted[c + lane] : -1;
                    int mm = min(64, end - c);
                    for (int j = 0; j < mm; ++j) {
                        unsigned qq = (unsigned)__shfl(sv, j);
                        int rel = (int)(qq >> 16); int src = (int)(qq & 0xFFFFu);
                        float cf = __shfl(myCntF, rel);
                        float norm = __builtin_amdgcn_rcpf(fmaxf(cf, 1.0f));
                        float2 cwf = comp_lds[rel * 4 + bs];
                        f32x2 w; w.x = cwf.x * norm; w.y = cwf.y * norm;
                        #pragma unroll
                        for (int i = 0; i < 8; ++i) {
                            float xv = xf[(size_t)src * NDIM + dg * 8 + i];
                            f32x2 v2 = {xv, xv};
                            acc[i] += w * v2;
                        }
                    }
                }
            }
        }

        unsigned short* row = &A_lds[wave * APITCH];
        uint4 p0, p1;
        p0.x = pack2bf(acc[0].x, acc[1].x); p0.y = pack2bf(acc[2].x, acc[3].x);
        p0.z = pack2bf(acc[4].x, acc[5].x); p0.w = pack2bf(acc[6].x, acc[7].x);
        p1.x = pack2bf(acc[0].y, acc[1].y); p1.y = pack2bf(acc[2].y, acc[3].y);
        p1.z = pack2bf(acc[4].y, acc[5].y); p1.w = pack2bf(acc[6].y, acc[7].y);
        *(uint4*)(row + (bs * 2 + 0) * NDIM + dg * 8) = p0;
        *(uint4*)(row + (bs * 2 + 1) * NDIM + dg * 8) = p1;
        if (bs == 0) {   // root slot
            uint4 xr = {0, 0, 0, 0};
            if (n < N) {
                if (!isf32) {
                    xr = *(const uint4*)((const unsigned short*)x + (size_t)n * NDIM + dg * 8);
                } else {
                    const float* xf = (const float*)x + (size_t)n * NDIM + dg * 8;
                    xr.x = pack2bf(xf[0], xf[1]); xr.y = pack2bf(xf[2], xf[3]);
                    xr.z = pack2bf(xf[4], xf[5]); xr.w = pack2bf(xf[6], xf[7]);
                }
            }
            *(uint4*)(row + NBASES * NDIM + dg * 8) = xr;
        }
    }
    __syncthreads();

    // ---- Phase B: [16,1152] @ [1152,128]; waves 0..7, 16 cols each ----
    const int m = lane & 15;
    const int q = lane >> 4;
    const bool doB = (wave < 8);
    f32x4 C = {0, 0, 0, 0};
    if (doB) {
        const unsigned short* arow = &A_lds[m * APITCH];
        const unsigned short* brow = BT + (size_t)(wave * 16 + m) * KDIM;
        #pragma unroll 1
        for (int g = 0; g < 9; ++g) {         // 36 K-steps, 4 per group
            int kb = g * 128 + q * 8;
            bfrag a0 = *(const bfrag*)(arow + kb);
            bfrag a1 = *(const bfrag*)(arow + kb + 32);
            bfrag a2 = *(const bfrag*)(arow + kb + 64);
            bfrag a3 = *(const bfrag*)(arow + kb + 96);
            bfrag b0 = *(const bfrag*)(brow + kb);
            bfrag b1 = *(const bfrag*)(brow + kb + 32);
            bfrag b2 = *(const bfrag*)(brow + kb + 64);
            bfrag b3 = *(const bfrag*)(brow + kb + 96);
            C = __builtin_amdgcn_mfma_f32_16x16x32_bf16(a0, b0, C, 0, 0, 0);
            C = __builtin_amdgcn_mfma_f32_16x16x32_bf16(a1, b1, C, 0, 0, 0);
            C = __builtin_amdgcn_mfma_f32_16x16x32_bf16(a2, b2, C, 0, 0, 0);
            C = __builtin_amdgcn_mfma_f32_16x16x32_bf16(a3, b3, C, 0, 0, 0);
        }
    }
    __syncthreads();            // all waves done reading A_lds
    if (doB) {
        int j = wave * 16 + m;
        float bj = loadF(bias, j, isf32);
        if (isf32) {
            #pragma unroll
            for (int r = 0; r < 4; ++r) {
                int n = nodeBase + q * 4 + r;
                if (n < N) ((float*)out)[(size_t)n * NDIM + j] = C[r] + bj;
            }
        } else {
            // stage C (bf16) into A_lds[0..2047] as [16 rows][128 cols]
            #pragma unroll
            for (int r = 0; r < 4; ++r)
                A_lds[(q * 4 + r) * NDIM + j] = f2bf(C[r] + bj);
        }
    }
    __syncthreads();
    if (!isf32) {               // coalesced row store: wave g writes row g
        int n = nodeBase + wave;
        if (n < N)
            ((unsigned*)out)[(size_t)n * (NDIM / 2) + lane] =
                ((const unsigned*)A_lds)[wave * (NDIM / 2) + lane];
    }
}

extern "C" void kernel_launch(void* const* d_in, const int* in_sizes, int n_in,
                              void* d_out, int out_size, void* d_ws, size_t ws_size,
                              hipStream_t stream) {
    const int* ei = (const int*)d_in[0];
    const int* et = (const int*)d_in[1];

    const int E = in_sizes[1];
    const int N = in_sizes[2] / NDIM;
    const int S = in_sizes[7] / NDIM;

    // workspace layout — round-2-proven footprint (~3.29 MB)
    char* ws = (char*)d_ws;
    int* meta    = (int*)ws;                                   // 4 ints
    int* hist    = (int*)(ws + 16);                            // N
    int* cursor  = (int*)(ws + 16 + (size_t)N * 4);            // N
    int* offsets = (int*)(ws + 16 + (size_t)2 * N * 4);        // N+1
    size_t off_bt = (16 + (size_t)(3 * N + 1) * 4 + 15) & ~(size_t)15;
    unsigned short* BT = (unsigned short*)(ws + off_bt);       // 128*1152 bf16
    size_t off_sorted = (off_bt + (size_t)NDIM * KDIM * 2 + 15) & ~(size_t)15;
    int* sorted = (int*)(ws + off_sorted);                     // E

    hipMemsetAsync(ws + 16, 0, (size_t)2 * N * 4, stream);     // hist + cursor

    detect_k<<<1, 64, 0, stream>>>((const unsigned short*)d_in[2], ei, meta);
    misc_k<<<(NDIM * KDIM + S * NDIM + 255) / 256, 256, 0, stream>>>(
        d_in[3], d_in[5], d_in[7], meta, BT, d_out, S * NDIM, N * NDIM);
    hist_k<<<(E + 255) / 256, 256, 0, stream>>>(ei, E, N, meta, hist);
    scan_k<<<1, 1024, 0, stream>>>(hist, N, offsets);
    scatter_k<<<(E + 255) / 256, 256, 0, stream>>>(ei, et, E, N, meta, offsets, cursor, sorted);
    rgcn_main_k<<<(N + GTILE - 1) / GTILE, 1024, 0, stream>>>(d_in[2], d_in[4], d_in[6], BT,
                                                              meta, offsets, sorted, d_out, N);
}

// Round 8
// 341.019 us; speedup vs baseline: 1.4169x; 1.4169x over previous
//
#include <hip/hip_runtime.h>

#define NDIM 128
#define NBASES 8
#define KDIM 1152            // 8*128 (bases) + 128 (root slot)
#define GTILE 16
#define APITCH 1160          // shorts; row stride 2320 B (16B-divisible)

typedef __attribute__((ext_vector_type(8))) __bf16 bfrag;
typedef __attribute__((ext_vector_type(4))) float f32x4;

__device__ __forceinline__ float bf2f(unsigned short b) {
    return __uint_as_float(((unsigned)b) << 16);
}
__device__ __forceinline__ unsigned short f2bf(float f) {
    unsigned u = __float_as_uint(f);
    unsigned r = u + 0x7FFFu + ((u >> 16) & 1u);   // RNE
    return (unsigned short)(r >> 16);
}
__device__ __forceinline__ unsigned pack2bf(float lo, float hi) {
    return (unsigned)f2bf(lo) | ((unsigned)f2bf(hi) << 16);
}
__device__ __forceinline__ float loadF(const void* p, int idx, int isf32) {
    return isf32 ? ((const float*)p)[idx] : bf2f(((const unsigned short*)p)[idx]);
}

// ---------- dtype sniffing (R7-proven ILP version) ----------
__global__ void detect_k(const unsigned short* __restrict__ xs,
                         const int* __restrict__ ei, int* __restrict__ meta) {
    if (threadIdx.x != 0 || blockIdx.x != 0) return;
    const uint4* xv = (const uint4*)xs;
    unsigned f32m = 0;
    uint4 bx[16];
    #pragma unroll
    for (int i = 0; i < 16; ++i) bx[i] = xv[i];
    #pragma unroll
    for (int i = 0; i < 16; ++i) {
        unsigned a = bx[i].x, b = bx[i].y, c = bx[i].z, d = bx[i].w;
        f32m |= (((a & 0xFFFFu) >> 7) & 0xFFu) > 124u;
        f32m |= (((b & 0xFFFFu) >> 7) & 0xFFu) > 124u;
        f32m |= (((c & 0xFFFFu) >> 7) & 0xFFu) > 124u;
        f32m |= (((d & 0xFFFFu) >> 7) & 0xFFu) > 124u;
    }
    const uint4* ev = (const uint4*)ei;
    unsigned nzm = 0;
    for (int r = 0; r < 4; ++r) {
        uint4 be[16];
        #pragma unroll
        for (int i = 0; i < 16; ++i) be[i] = ev[r * 16 + i];
        #pragma unroll
        for (int i = 0; i < 16; ++i) nzm |= be[i].y | be[i].w;
    }
    meta[0] = f32m ? 1 : 0;
    meta[1] = nzm ? 0 : 1;
}

// merged: BT build + special-embedding copy (R7-proven)
__global__ void misc_k(const void* __restrict__ basis, const void* __restrict__ root,
                       const void* __restrict__ se, const int* __restrict__ meta,
                       unsigned short* __restrict__ BT, void* __restrict__ out,
                       int scount, int sbase) {
    int t = blockIdx.x * 256 + threadIdx.x;
    int isf32 = meta[0];
    if (t < NDIM * KDIM) {
        int j = t / KDIM, k = t % KDIM;
        float v = (k < NBASES * NDIM) ? loadF(basis, k * NDIM + j, isf32)
                                      : loadF(root, (k - NBASES * NDIM) * NDIM + j, isf32);
        BT[t] = f2bf(v);
    } else {
        int u = t - NDIM * KDIM;
        if (u < scount) {
            float v = loadF(se, u, isf32);
            if (isf32) ((float*)out)[sbase + u] = v;
            else       ((unsigned short*)out)[sbase + u] = f2bf(v);
        }
    }
}

__global__ void hist_k(const int* __restrict__ ei, int E, int N,
                       const int* __restrict__ meta, int* __restrict__ hist) {
    int e = blockIdx.x * 256 + threadIdx.x;
    if (e >= E) return;
    int dst = meta[1] ? ei[2 * (E + e)] : ei[E + e];
    dst = min(max(dst, 0), N - 1);
    atomicAdd(&hist[dst], 1);
}

// ---------- hierarchical exclusive scan (uniform control flow, no shfl) ----------
__global__ void scanA_k(const int* __restrict__ hist, int N,
                        int* __restrict__ offsets, int* __restrict__ bsum) {
    __shared__ int s[1024];
    int tid = threadIdx.x;
    int idx = blockIdx.x * 1024 + tid;
    int v = (idx < N) ? hist[idx] : 0;
    s[tid] = v;
    __syncthreads();
    for (int off = 1; off < 1024; off <<= 1) {
        int t = 0;
        if (tid >= off) t = s[tid - off];
        __syncthreads();
        if (tid >= off) s[tid] += t;
        __syncthreads();
    }
    if (idx < N) offsets[idx] = s[tid] - v;           // exclusive within block
    if (tid == 1023) bsum[blockIdx.x] = s[1023];
}
__global__ void scanB_k(const int* __restrict__ bsum, int NB, int N,
                        int* __restrict__ bpre, int* __restrict__ offsets) {
    __shared__ int s[64];
    int tid = threadIdx.x;
    int v = (tid < NB) ? bsum[tid] : 0;
    s[tid] = v;
    __syncthreads();
    for (int off = 1; off < 64; off <<= 1) {
        int t = 0;
        if (tid >= off) t = s[tid - off];
        __syncthreads();
        if (tid >= off) s[tid] += t;
        __syncthreads();
    }
    if (tid < NB) bpre[tid] = s[tid] - v;
    if (tid == NB - 1) offsets[N] = s[tid];
}
__global__ void scanC_k(int N, const int* __restrict__ bpre, int* __restrict__ offsets) {
    int idx = blockIdx.x * 1024 + threadIdx.x;
    if (idx < N) offsets[idx] += bpre[blockIdx.x];
}

__global__ void scatter_k(const int* __restrict__ ei, const int* __restrict__ et,
                          int E, int N, const int* __restrict__ meta,
                          const int* __restrict__ offsets, int* __restrict__ cursor,
                          int* __restrict__ sorted) {
    int e = blockIdx.x * 256 + threadIdx.x;
    if (e >= E) return;
    int i64 = meta[1];
    int src = i64 ? ei[2 * e] : ei[e];
    int dst = i64 ? ei[2 * (E + e)] : ei[E + e];
    int rel = i64 ? et[2 * e] : et[e];
    src = min(max(src, 0), N - 1);
    dst = min(max(dst, 0), N - 1);
    rel = rel & 63;
    int pos = offsets[dst] + atomicAdd(&cursor[dst], 1);
    sorted[pos] = src | (rel << 16);
}

// ---------- main fused kernel: R6-proven (194 us) ----------
__global__ __launch_bounds__(1024) void rgcn_main_k(
    const void* __restrict__ x, const void* __restrict__ comp,
    const void* __restrict__ bias, const unsigned short* __restrict__ BT,
    const int* __restrict__ meta, const int* __restrict__ offsets,
    const int* __restrict__ sorted, void* __restrict__ out, int N)
{
    __shared__ alignas(16) unsigned short A_lds[GTILE * APITCH];   // 37120 B
    __shared__ float2 comp_lds[48 * 4];                            // [rel][bs]
    const int tid  = threadIdx.x;
    const int lane = tid & 63;
    const int wave = tid >> 6;
    const int isf32 = meta[0];

    for (int t = tid; t < 48 * NBASES; t += 1024)
        ((float*)comp_lds)[t] = loadF(comp, t, isf32);
    __syncthreads();

    const int nodeBase = blockIdx.x * GTILE;
    const int dg = lane & 15;    // dim group: dims dg*8..+8
    const int bs = lane >> 4;    // basis slot: bases bs*2, bs*2+1

    {   // ---- Phase A: this wave's node ----
        const int n = nodeBase + wave;
        float acc0[8], acc1[8];
        #pragma unroll
        for (int i = 0; i < 8; ++i) { acc0[i] = 0.f; acc1[i] = 0.f; }

        if (n < N) {
            const int start = offsets[n], end = offsets[n + 1];

            // pass 1: per-relation counts, VALU-only (uniform trip count!)
            int myCnt = 0;
            for (int c = start; c < end; c += 64) {
                int sv = (c + lane < end) ? sorted[c + lane] : -1;
                int mm = min(64, end - c);
                for (int j = 0; j < mm; ++j) {
                    int rv = __shfl(sv, j) >> 16;
                    myCnt += (rv == lane) ? 1 : 0;
                }
            }
            float myCntF = (float)myCnt;

            // pass 2: gather + accumulate, 4-deep pipelined gathers
            if (!isf32) {
                const unsigned short* xh = (const unsigned short*)x;
                for (int c = start; c < end; c += 64) {
                    int sv = (c + lane < end) ? sorted[c + lane] : -1;
                    int mm = min(64, end - c);
                    int j = 0;
                    for (; j + 4 <= mm; j += 4) {
                        unsigned q0 = (unsigned)__shfl(sv, j);
                        unsigned q1 = (unsigned)__shfl(sv, j + 1);
                        unsigned q2 = (unsigned)__shfl(sv, j + 2);
                        unsigned q3 = (unsigned)__shfl(sv, j + 3);
                        uint4 x0 = *(const uint4*)(xh + (size_t)(q0 & 0xFFFFu) * NDIM + dg * 8);
                        uint4 x1 = *(const uint4*)(xh + (size_t)(q1 & 0xFFFFu) * NDIM + dg * 8);
                        uint4 x2 = *(const uint4*)(xh + (size_t)(q2 & 0xFFFFu) * NDIM + dg * 8);
                        uint4 x3 = *(const uint4*)(xh + (size_t)(q3 & 0xFFFFu) * NDIM + dg * 8);
                        #pragma unroll
                        for (int u = 0; u < 4; ++u) {
                            unsigned qq = (u == 0) ? q0 : (u == 1) ? q1 : (u == 2) ? q2 : q3;
                            uint4  xa = (u == 0) ? x0 : (u == 1) ? x1 : (u == 2) ? x2 : x3;
                            int rel = (int)(qq >> 16);
                            float cf = __shfl(myCntF, rel);
                            float norm = 1.0f / fmaxf(cf, 1.0f);
                            float2 cw = comp_lds[rel * 4 + bs];
                            float w0 = cw.x * norm, w1 = cw.y * norm;
                            #pragma unroll
                            for (int i = 0; i < 4; ++i) {
                                float lo = __uint_as_float(xa[i] << 16);
                                float hi = __uint_as_float(xa[i] & 0xFFFF0000u);
                                acc0[2*i]   += w0 * lo;  acc0[2*i+1] += w0 * hi;
                                acc1[2*i]   += w1 * lo;  acc1[2*i+1] += w1 * hi;
                            }
                        }
                    }
                    for (; j < mm; ++j) {
                        unsigned qq = (unsigned)__shfl(sv, j);
                        int rel = (int)(qq >> 16);
                        float cf = __shfl(myCntF, rel);
                        float norm = 1.0f / fmaxf(cf, 1.0f);
                        float2 cw = comp_lds[rel * 4 + bs];
                        float w0 = cw.x * norm, w1 = cw.y * norm;
                        uint4 xa = *(const uint4*)(xh + (size_t)(qq & 0xFFFFu) * NDIM + dg * 8);
                        #pragma unroll
                        for (int i = 0; i < 4; ++i) {
                            float lo = __uint_as_float(xa[i] << 16);
                            float hi = __uint_as_float(xa[i] & 0xFFFF0000u);
                            acc0[2*i]   += w0 * lo;  acc0[2*i+1] += w0 * hi;
                            acc1[2*i]   += w1 * lo;  acc1[2*i+1] += w1 * hi;
                        }
                    }
                }
            } else {
                const float* xf = (const float*)x;
                for (int c = start; c < end; c += 64) {
                    int sv = (c + lane < end) ? sorted[c + lane] : -1;
                    int mm = min(64, end - c);
                    for (int j = 0; j < mm; ++j) {
                        unsigned qq = (unsigned)__shfl(sv, j);
                        int rel = (int)(qq >> 16); int src = (int)(qq & 0xFFFFu);
                        float cf = __shfl(myCntF, rel);
                        float norm = 1.0f / fmaxf(cf, 1.0f);
                        float2 cw = comp_lds[rel * 4 + bs];
                        float w0 = cw.x * norm, w1 = cw.y * norm;
                        #pragma unroll
                        for (int i = 0; i < 8; ++i) {
                            float xv = xf[(size_t)src * NDIM + dg * 8 + i];
                            acc0[i] += w0 * xv; acc1[i] += w1 * xv;
                        }
                    }
                }
            }
        }

        unsigned short* row = &A_lds[wave * APITCH];
        uint4 p0, p1;
        p0.x = pack2bf(acc0[0], acc0[1]); p0.y = pack2bf(acc0[2], acc0[3]);
        p0.z = pack2bf(acc0[4], acc0[5]); p0.w = pack2bf(acc0[6], acc0[7]);
        p1.x = pack2bf(acc1[0], acc1[1]); p1.y = pack2bf(acc1[2], acc1[3]);
        p1.z = pack2bf(acc1[4], acc1[5]); p1.w = pack2bf(acc1[6], acc1[7]);
        *(uint4*)(row + (bs * 2 + 0) * NDIM + dg * 8) = p0;
        *(uint4*)(row + (bs * 2 + 1) * NDIM + dg * 8) = p1;
        if (bs == 0) {   // root slot: node's own embedding
            uint4 xr = {0, 0, 0, 0};
            if (n < N) {
                if (!isf32) {
                    xr = *(const uint4*)((const unsigned short*)x + (size_t)n * NDIM + dg * 8);
                } else {
                    const float* xf = (const float*)x + (size_t)n * NDIM + dg * 8;
                    xr.x = pack2bf(xf[0], xf[1]); xr.y = pack2bf(xf[2], xf[3]);
                    xr.z = pack2bf(xf[4], xf[5]); xr.w = pack2bf(xf[6], xf[7]);
                }
            }
            *(uint4*)(row + NBASES * NDIM + dg * 8) = xr;
        }
    }
    __syncthreads();

    // ---- Phase B: [16,1152] @ [1152,128], waves 0..3, 32 cols each ----
    if (wave < 4) {
        const int m = lane & 15;
        const int q = lane >> 4;
        f32x4 C0 = {0,0,0,0}, C1 = {0,0,0,0};
        const unsigned short* arow = &A_lds[m * APITCH];
        const int jb = wave * 32;
        for (int ks = 0; ks < KDIM / 32; ++ks) {
            int k = ks * 32 + q * 8;
            bfrag a  = *(const bfrag*)(arow + k);
            bfrag b0 = *(const bfrag*)(BT + (size_t)(jb +  0 + m) * KDIM + k);
            bfrag b1 = *(const bfrag*)(BT + (size_t)(jb + 16 + m) * KDIM + k);
            C0 = __builtin_amdgcn_mfma_f32_16x16x32_bf16(a, b0, C0, 0, 0, 0);
            C1 = __builtin_amdgcn_mfma_f32_16x16x32_bf16(a, b1, C1, 0, 0, 0);
        }
        // C/D layout (m89/m91): col = lane&15, row = (lane>>4)*4 + reg
        #pragma unroll
        for (int t = 0; t < 2; ++t) {
            f32x4 Ct = t ? C1 : C0;
            int j = jb + t * 16 + m;
            float bj = loadF(bias, j, isf32);
            #pragma unroll
            for (int r = 0; r < 4; ++r) {
                int n = nodeBase + q * 4 + r;
                if (n < N) {
                    float v = Ct[r] + bj;
                    if (isf32) ((float*)out)[(size_t)n * NDIM + j] = v;
                    else       ((unsigned short*)out)[(size_t)n * NDIM + j] = f2bf(v);
                }
            }
        }
    }
}

extern "C" void kernel_launch(void* const* d_in, const int* in_sizes, int n_in,
                              void* d_out, int out_size, void* d_ws, size_t ws_size,
                              hipStream_t stream) {
    const int* ei = (const int*)d_in[0];
    const int* et = (const int*)d_in[1];

    const int E = in_sizes[1];
    const int N = in_sizes[2] / NDIM;
    const int S = in_sizes[7] / NDIM;
    const int NB = (N + 1023) / 1024;

    // workspace layout — ~3.30 MB (R2-proven footprint + 512 B scan temps)
    char* ws = (char*)d_ws;
    size_t off = 0;
    int* meta    = (int*)(ws + off); off += 16;
    int* hist    = (int*)(ws + off); off += (size_t)N * 4;
    int* cursor  = (int*)(ws + off); off += (size_t)N * 4;
    int* offsets = (int*)(ws + off); off = (off + (size_t)(N + 1) * 4 + 15) & ~(size_t)15;
    int* bsum    = (int*)(ws + off); off += 64 * 4;
    int* bpre    = (int*)(ws + off); off += 64 * 4;
    unsigned short* BT = (unsigned short*)(ws + off); off += (size_t)NDIM * KDIM * 2;
    int* sorted  = (int*)(ws + off); off += (size_t)E * 4;

    hipMemsetAsync(hist, 0, (size_t)2 * N * 4, stream);   // hist + cursor

    detect_k<<<1, 64, 0, stream>>>((const unsigned short*)d_in[2], ei, meta);
    misc_k<<<(NDIM * KDIM + S * NDIM + 255) / 256, 256, 0, stream>>>(
        d_in[3], d_in[5], d_in[7], meta, BT, d_out, S * NDIM, N * NDIM);
    hist_k<<<(E + 255) / 256, 256, 0, stream>>>(ei, E, N, meta, hist);
    scanA_k<<<NB, 1024, 0, stream>>>(hist, N, offsets, bsum);
    scanB_k<<<1, 64, 0, stream>>>(bsum, NB, N, bpre, offsets);
    scanC_k<<<NB, 1024, 0, stream>>>(N, bpre, offsets);
    scatter_k<<<(E + 255) / 256, 256, 0, stream>>>(ei, et, E, N, meta, offsets, cursor, sorted);
    rgcn_main_k<<<(N + GTILE - 1) / GTILE, 1024, 0, stream>>>(d_in[2], d_in[4], d_in[6], BT,
                                                              meta, offsets, sorted, d_out, N);
}